// Round 9
// baseline (181.586 us; speedup 1.0000x reference)
//
#include <hip/hip_runtime.h>
#include <cmath>

// x[32768, 256] fp32, codebook[1024, 256] fp32. Outputs fp32 flat:
// loss(1), z_q(8388608), perplexity(1), indices(32768)
#define NROWS 32768
#define DDIM  256
#define KCB   1024

// 2-term split dot with A scaled by -2: dist = cn + (a_hi*b_hi + a_lo*b_hi)
// where a = -2x split into fp16 hi+lo (exact residual), b = codebook fp16-hi.
// Dist error eps_max ~0.05; TAU=0.25 > 2*eps with 2.5x margin (validated
// r5-r7). v2-v1 < TAU -> in-block wave-parallel fp64 pair-compare (~6/block).
// v3-v1 < TAU -> in-block block-cooperative fp64 full rescan (~0.24/block,
// ~1.8us each; Poisson-max tail ~7us). NO cleanup kernel: its dispatch alone
// cost ~40us (r6/r7 ledger: Delta 106 vs 64-68 for 2-4 tiny launches).
// Loss/perp finalized by last-done block (r5-validated done-counter).
constexpr float TAU = 0.25f;
constexpr int BSTR = 264;      // validated conflict-free stride (528 B/row)

typedef _Float16 half8 __attribute__((ext_vector_type(8)));
typedef _Float16 half4 __attribute__((ext_vector_type(4)));
typedef float floatx4 __attribute__((ext_vector_type(4)));

// Exact codebook norms (fp64 -> fp32); optional fp16 codebook copy (H);
// block 0 also zero-inits the accumulators.
template<bool CVT>
__global__ __launch_bounds__(64) void prep_kernel(const float* __restrict__ cb,
                                                  float* __restrict__ cn,
                                                  _Float16* __restrict__ cbh,
                                                  double* __restrict__ sumsq,
                                                  int* __restrict__ sumidx,
                                                  unsigned* __restrict__ done) {
  const int k = blockIdx.x, lane = threadIdx.x;
  if (k == 0 && lane == 0) { *sumsq = 0.0; *sumidx = 0; *done = 0u; }
  float4 v = *(const float4*)(cb + (size_t)k * DDIM + lane * 4);
  if constexpr (CVT) {
    half4 h;
    h[0] = (_Float16)v.x; h[1] = (_Float16)v.y;
    h[2] = (_Float16)v.z; h[3] = (_Float16)v.w;
    *(half4*)&cbh[(size_t)k * DDIM + lane * 4] = h;
  }
  double s = (double)v.x * v.x + (double)v.y * v.y
           + (double)v.z * v.z + (double)v.w * v.w;
  #pragma unroll
  for (int off = 32; off; off >>= 1) s += __shfl_down(s, off);
  if (lane == 0) cn[k] = (float)s;
}

// Block = 256 thr / 4 waves / 64 rows. Grid 512 = 2 blocks/CU (LDS ~41 KB).
// Stage = 32 codebook entries x 256 dims fp16-hi in 32xBSTR layout, dbuf.
// H: staged straight from prep's fp16 copy (pure 16B copy, no cvt VALU).
template<bool H>
__global__ __launch_bounds__(256, 2) void fused_kernel(
    const float* __restrict__ x,
    const float* __restrict__ cb,
    const _Float16* __restrict__ cbh,
    const float* __restrict__ cn,
    float* __restrict__ zq_out,
    float* __restrict__ idx_out,
    float* __restrict__ out_loss,
    float* __restrict__ out_perp,
    double* __restrict__ sumsq,
    int* __restrict__ sumidx,
    unsigned* __restrict__ done) {
  __shared__ __align__(16) _Float16 bs[2][32 * BSTR];  // 2 x 16.9 KB tiles
  __shared__ float cn_lds[KCB];
  __shared__ int   bidx[64];     // best index
  __shared__ int   bidx2[64];    // second-best index
  __shared__ float m2s[64];      // v2 - v1
  __shared__ float m3s[64];      // v3 - v1
  __shared__ __align__(16) float xrow[DDIM];
  __shared__ int   plist[64];    // pair-recheck rows
  __shared__ int   flist[64];    // full-rescan rows
  __shared__ int   npair, nflag;
  __shared__ float wred[4];
  __shared__ double rv[4];
  __shared__ int    ri[4];

  const int tid = threadIdx.x;
  const int lane = tid & 63;
  const int w = tid >> 6;        // wave 0..3: rows w*16 .. +15
  const int q = lane >> 4;       // quad
  const int tx = lane & 15;
  const int row0 = blockIdx.x * 64;

  // ---- A fragments (-2x, hi+lo): lane holds rows row0+w*16+tx ----
  half8 a_hi[8], a_lo[8];
  {
    const float* xp = x + (size_t)(row0 + w * 16 + tx) * DDIM + q * 8;
    #pragma unroll
    for (int s = 0; s < 8; ++s) {
      float4 v0 = *(const float4*)(xp + s * 32);
      float4 v1 = *(const float4*)(xp + s * 32 + 4);
      half8 h, l;
      _Float16 t; float sx;
      sx = -2.f * v0.x; t = (_Float16)sx; h[0] = t; l[0] = (_Float16)(sx - (float)t);
      sx = -2.f * v0.y; t = (_Float16)sx; h[1] = t; l[1] = (_Float16)(sx - (float)t);
      sx = -2.f * v0.z; t = (_Float16)sx; h[2] = t; l[2] = (_Float16)(sx - (float)t);
      sx = -2.f * v0.w; t = (_Float16)sx; h[3] = t; l[3] = (_Float16)(sx - (float)t);
      sx = -2.f * v1.x; t = (_Float16)sx; h[4] = t; l[4] = (_Float16)(sx - (float)t);
      sx = -2.f * v1.y; t = (_Float16)sx; h[5] = t; l[5] = (_Float16)(sx - (float)t);
      sx = -2.f * v1.z; t = (_Float16)sx; h[6] = t; l[6] = (_Float16)(sx - (float)t);
      sx = -2.f * v1.w; t = (_Float16)sx; h[7] = t; l[7] = (_Float16)(sx - (float)t);
      a_hi[s] = h; a_lo[s] = l;
    }
  }
  #pragma unroll
  for (int i = 0; i < 4; ++i) cn_lds[tid + 256 * i] = cn[tid + 256 * i];
  if (tid == 0) { npair = 0; nflag = 0; }

  // stage ct covers entries ct*32..+31 (8192 halves). 16B unit u = tid+256*i
  // (i 0..3): entry e = u>>5, chunk c = u&31.
  half8 vld[4];
  float4 vldf[8];
  auto load_stage = [&](int ct) {
    #pragma unroll
    for (int i = 0; i < 4; ++i) {
      int u = tid + 256 * i;
      if constexpr (H) {
        vld[i] = *(const half8*)&cbh[(size_t)ct * 8192 + (size_t)u * 8];
      } else {
        const float* src = cb + (size_t)ct * 8192 + (size_t)u * 8;
        vldf[2 * i]     = *(const float4*)src;
        vldf[2 * i + 1] = *(const float4*)(src + 4);
      }
    }
  };
  auto write_stage = [&](int buf) {
    #pragma unroll
    for (int i = 0; i < 4; ++i) {
      int u = tid + 256 * i;
      int e = u >> 5, c = u & 31;
      if constexpr (H) {
        *(half8*)&bs[buf][e * BSTR + c * 8] = vld[i];
      } else {
        float4 v0 = vldf[2 * i], v1 = vldf[2 * i + 1];
        half8 h;
        h[0] = (_Float16)v0.x; h[1] = (_Float16)v0.y;
        h[2] = (_Float16)v0.z; h[3] = (_Float16)v0.w;
        h[4] = (_Float16)v1.x; h[5] = (_Float16)v1.y;
        h[6] = (_Float16)v1.z; h[7] = (_Float16)v1.w;
        *(half8*)&bs[buf][e * BSTR + c * 8] = h;
      }
    }
  };

  // top-3 values + top-2 indices per owned row r (ascending v1<=v2<=v3)
  float v1[4], v2[4], v3[4];
  int i1[4], i2[4];
  #pragma unroll
  for (int r = 0; r < 4; ++r) {
    v1[r] = INFINITY; v2[r] = INFINITY; v3[r] = INFINITY; i1[r] = 0; i2[r] = 0;
  }

  load_stage(0);
  for (int st = 0; st < 32; ++st) {
    const int buf = st & 1;
    write_stage(buf);            // consumes loads issued last iter (vmcnt wait)
    __syncthreads();             // tile visible; prev tile's readers done
    if (st + 1 < 32) load_stage(st + 1);   // in flight across compute(st)

    floatx4 ahh[2], alh[2];
    #pragma unroll
    for (int ci = 0; ci < 2; ++ci) {
      ahh[ci] = (floatx4){0.f, 0.f, 0.f, 0.f};
      alh[ci] = (floatx4){0.f, 0.f, 0.f, 0.f};
    }

    #pragma unroll
    for (int s = 0; s < 8; ++s) {
      #pragma unroll
      for (int ci = 0; ci < 2; ++ci) {
        half8 bh = *(const half8*)&bs[buf][(ci * 16 + tx) * BSTR + (s * 4 + q) * 8];
        ahh[ci] = __builtin_amdgcn_mfma_f32_16x16x32_f16(a_hi[s], bh, ahh[ci], 0, 0, 0);
        alh[ci] = __builtin_amdgcn_mfma_f32_16x16x32_f16(a_lo[s], bh, alh[ci], 0, 0, 0);
      }
    }

    // epilogue: C/D layout col=lane&15, row=q*4+reg; dist = cn + (-2x . b)
    #pragma unroll
    for (int ci = 0; ci < 2; ++ci) {
      int col = st * 32 + ci * 16 + tx;
      float cnv = cn_lds[col];
      #pragma unroll
      for (int r = 0; r < 4; ++r) {
        float dist = cnv + (ahh[ci][r] + alh[ci][r]);
        if (dist < v1[r]) {
          v3[r] = v2[r]; v2[r] = v1[r]; i2[r] = i1[r];
          v1[r] = dist; i1[r] = col;
        } else if (dist < v2[r]) {
          v3[r] = v2[r]; v2[r] = dist; i2[r] = col;
        } else if (dist < v3[r]) {
          v3[r] = dist;
        }
      }
    }
  }

  // merge top-3 (+ top-2 idx) across the 16 tx-lanes of each quad
  #pragma unroll
  for (int off = 8; off; off >>= 1) {
    #pragma unroll
    for (int r = 0; r < 4; ++r) {
      float ov1 = __shfl_down(v1[r], off, 16);
      int   oi1 = __shfl_down(i1[r], off, 16);
      float ov2 = __shfl_down(v2[r], off, 16);
      int   oi2 = __shfl_down(i2[r], off, 16);
      float ov3 = __shfl_down(v3[r], off, 16);
      bool takeo = (ov1 < v1[r]) || (ov1 == v1[r] && oi1 < i1[r]);
      float n1v = takeo ? ov1 : v1[r];
      int   n1i = takeo ? oi1 : i1[r];
      float l1 = takeo ? v1[r] : v2[r];
      int   l1i = takeo ? i1[r] : i2[r];
      float l2 = takeo ? v2[r] : v3[r];
      float r1 = takeo ? ov2 : ov1;
      int   r1i = takeo ? oi2 : oi1;
      float r2 = takeo ? ov3 : ov2;
      bool t2 = (r1 < l1) || (r1 == l1 && r1i < l1i);
      float n2v = t2 ? r1 : l1;
      int   n2i = t2 ? r1i : l1i;
      float n3v = t2 ? fminf(r2, l1) : fminf(l2, r1);
      v1[r] = n1v; i1[r] = n1i; v2[r] = n2v; i2[r] = n2i; v3[r] = n3v;
    }
  }
  if (tx == 0) {
    #pragma unroll
    for (int r = 0; r < 4; ++r) {
      int R = w * 16 + q * 4 + r;
      bidx[R]  = i1[r];
      bidx2[R] = i2[r];
      m2s[R] = v2[r] - v1[r];
      m3s[R] = v3[r] - v1[r];
    }
  }
  __syncthreads();

  if (tid < 64) {
    if (m3s[tid] < TAU) {                       // >=2 rivals: full rescan
      int p = atomicAdd(&nflag, 1);
      flist[p] = tid;
    } else if (m2s[tid] < TAU) {                // exactly one rival: pair check
      int p = atomicAdd(&npair, 1);
      plist[p] = tid;
    }
  }
  __syncthreads();

  // ---- full fp64 re-scan, block-cooperative: thread owns cols 4t..4t+3 ----
  for (int f = 0; f < nflag; ++f) {
    int r = flist[f];
    if (tid < 64) {
      float4 v = *(const float4*)(x + (size_t)(row0 + r) * DDIM + tid * 4);
      xrow[tid * 4 + 0] = v.x; xrow[tid * 4 + 1] = v.y;
      xrow[tid * 4 + 2] = v.z; xrow[tid * 4 + 3] = v.w;
    }
    __syncthreads();
    double bd = 1e300; int bi = 0;
    #pragma unroll
    for (int j = 0; j < 4; ++j) {
      int c = tid * 4 + j;                      // ascending: strict < keeps low
      const float* cp = cb + (size_t)c * DDIM;
      double s0 = 0.0, s1 = 0.0, s2 = 0.0, s3 = 0.0;
      for (int d = 0; d < DDIM; d += 4) {
        float4 cv = *(const float4*)(cp + d);
        float4 xv = *(const float4*)&xrow[d];   // LDS broadcast (same addr)
        double d0 = (double)xv.x - (double)cv.x; s0 = fma(d0, d0, s0);
        double d1 = (double)xv.y - (double)cv.y; s1 = fma(d1, d1, s1);
        double d2 = (double)xv.z - (double)cv.z; s2 = fma(d2, d2, s2);
        double d3 = (double)xv.w - (double)cv.w; s3 = fma(d3, d3, s3);
      }
      double s = (s0 + s1) + (s2 + s3);
      if (s < bd) { bd = s; bi = c; }
    }
    #pragma unroll
    for (int off = 32; off; off >>= 1) {
      double ov = __shfl_down(bd, off);
      int oi = __shfl_down(bi, off);
      if (ov < bd || (ov == bd && oi < bi)) { bd = ov; bi = oi; }
    }
    if (lane == 0) { rv[w] = bd; ri[w] = bi; }
    __syncthreads();
    if (tid == 0) {
      double bv = rv[0]; int bix = ri[0];
      #pragma unroll
      for (int ww = 1; ww < 4; ++ww)
        if (rv[ww] < bv || (rv[ww] == bv && ri[ww] < bix)) { bv = rv[ww]; bix = ri[ww]; }
      bidx[r] = bix;
    }
    __syncthreads();
  }

  // ---- fp64 pair-compare of {best, second}; waves take rows in parallel ----
  for (int f = w; f < npair; f += 4) {
    int r = plist[f];
    int cA = bidx[r], cB = bidx2[r];
    int c = (lane >= 32) ? cB : cA;
    int ld = lane & 31;                         // 32 lanes x 8 dims each
    const float* xp = x  + (size_t)(row0 + r) * DDIM + ld * 8;
    const float* cp = cb + (size_t)c * DDIM + ld * 8;
    double s = 0.0;
    #pragma unroll
    for (int j = 0; j < 8; j += 4) {
      float4 xv = *(const float4*)(xp + j);
      float4 cv = *(const float4*)(cp + j);
      double d0 = (double)xv.x - (double)cv.x; s = fma(d0, d0, s);
      double d1 = (double)xv.y - (double)cv.y; s = fma(d1, d1, s);
      double d2 = (double)xv.z - (double)cv.z; s = fma(d2, d2, s);
      double d3 = (double)xv.w - (double)cv.w; s = fma(d3, d3, s);
    }
    #pragma unroll
    for (int off = 16; off; off >>= 1) s += __shfl_xor(s, off);  // 32-lane halves
    double dA = __shfl(s, 0), dB = __shfl(s, 32);
    if (lane == 0) {
      bool takeB = (dB < dA) || (dB == dA && cB < cA);
      bidx[r] = takeB ? cB : cA;
    }
  }
  __syncthreads();

  if (tid < 64) idx_out[row0 + tid] = (float)bidx[tid];

  // ---- gather: z_q rows (exact fp32 copies) + loss partial ----
  float lsum = 0.f;
  #pragma unroll 4
  for (int it = 0; it < 16; ++it) {
    int g = tid + 256 * it;        // 4096 float4 groups = 64 rows x 64 groups
    int r = g >> 6;
    int c4 = (g & 63) << 2;
    int k = bidx[r] & (KCB - 1);
    float4 cv = *(const float4*)(cb + (size_t)k * DDIM + c4);
    float4 xv = *(const float4*)(x + (size_t)(row0 + r) * DDIM + c4);
    float d0 = cv.x - xv.x, d1 = cv.y - xv.y, d2 = cv.z - xv.z, d3 = cv.w - xv.w;
    lsum = fmaf(d0, d0, lsum); lsum = fmaf(d1, d1, lsum);
    lsum = fmaf(d2, d2, lsum); lsum = fmaf(d3, d3, lsum);
    *(float4*)(zq_out + (size_t)(row0 + r) * DDIM + c4) = cv;
  }
  #pragma unroll
  for (int off = 32; off; off >>= 1) lsum += __shfl_down(lsum, off);
  if (lane == 0) wred[w] = lsum;
  __syncthreads();
  if (tid == 0) {
    double ls = (double)wred[0] + (double)wred[1]
              + (double)wred[2] + (double)wred[3];
    atomicAdd(sumsq, ls);
    int si = 0;
    #pragma unroll 8
    for (int r = 0; r < 64; ++r) si += bidx[r] & (KCB - 1);
    atomicAdd(sumidx, si);

    // ---- last block finalizes loss/perplexity (r5-validated pattern) ----
    __threadfence();                            // order our adds before 'done'
    unsigned prev = atomicAdd(done, 1u);
    if (prev == gridDim.x - 1) {
      __threadfence();
      double ss = atomicAdd(sumsq, 0.0);        // device-scope atomic read
      int    sidx = atomicAdd(sumidx, 0);
      // loss = mean(sg(zq)-x)^2 + 0.25*mean(zq-sg(x))^2 = 1.25 * MSE
      double loss = 1.25 * ss / 8388608.0;
      double e_min = (double)sidx / 32768.0;    // scalar mean of indices
      double perp = exp(-e_min * log(e_min + 1e-10));
      *out_loss = (float)loss;
      *out_perp = (float)perp;
    }
  }
}

extern "C" void kernel_launch(void* const* d_in, const int* in_sizes, int n_in,
                              void* d_out, int out_size, void* d_ws, size_t ws_size,
                              hipStream_t stream) {
  const float* x  = (const float*)d_in[0];   // [32768, 256] fp32
  const float* cb = (const float*)d_in[1];   // [1024, 256] fp32
  float* out = (float*)d_out;
  float* out_loss = out;                  // [0]
  float* out_zq   = out + 1;              // [1 .. 8388608]
  float* out_perp = out + 1 + 8388608;    // [8388609]
  float* out_idx  = out + 2 + 8388608;    // [8388610 ..]

  double*   sumsq  = (double*)d_ws;
  int*      sumidx = (int*)((char*)d_ws + 8);
  unsigned* done   = (unsigned*)((char*)d_ws + 12);
  float*    cn     = (float*)((char*)d_ws + 64);        // 4 KB
  _Float16* cbh    = (_Float16*)((char*)d_ws + 8192);   // 512 KB

  // ws_size is launch-invariant => deterministic branch (r7 ran H=true).
  const bool useH = ws_size >= (size_t)(8192 + 524288);

  if (useH) {
    hipLaunchKernelGGL(prep_kernel<true>, dim3(KCB), dim3(64), 0, stream,
                       cb, cn, cbh, sumsq, sumidx, done);
    hipLaunchKernelGGL(fused_kernel<true>, dim3(NROWS / 64), dim3(256), 0, stream,
                       x, cb, cbh, cn, out_zq, out_idx, out_loss, out_perp,
                       sumsq, sumidx, done);
  } else {
    hipLaunchKernelGGL(prep_kernel<false>, dim3(KCB), dim3(64), 0, stream,
                       cb, cn, cbh, sumsq, sumidx, done);
    hipLaunchKernelGGL(fused_kernel<false>, dim3(NROWS / 64), dim3(256), 0, stream,
                       x, cb, cbh, cn, out_zq, out_idx, out_loss, out_perp,
                       sumsq, sumidx, done);
  }
}

// Round 10
// 160.810 us; speedup vs baseline: 1.1292x; 1.1292x over previous
//
#include <hip/hip_runtime.h>
#include <cmath>

// x[32768, 256] fp32, codebook[1024, 256] fp32. Outputs fp32 flat:
// loss(1), z_q(8388608), perplexity(1), indices(32768)
#define NROWS 32768
#define DDIM  256
#define KCB   1024

// 2-term split dot with A scaled by -2: dist = cn + (a_hi*b_hi + a_lo*b_hi),
// a = -2x in fp16 hi+lo (exact residual), b = codebook fp16-hi.
// eps_max ~0.05; TAU=0.25 > 2*eps with 2.5x margin (validated r5-r9).
// Measured margin stats (r6/r7/r9): P(m2<TAU)~9%/row, per-level ratio ~0.1.
// This round: per-lane top-4 (v,i) tracking -> per-row candidate list of all
// cols with approx dist < v1+TAU -> exact fp64 tournament (wave-parallel
// pair-checks). Full 1024-col fp64 rescan only if a lane's 4th entry is
// within TAU (eviction hazard) or >7 candidates: P ~ 1e-5/block -> the
// 10us/item rescan tail (64us in r9) vanishes.
constexpr float TAU = 0.25f;
constexpr int BSTR = 264;      // validated conflict-free stride (528 B/row)

typedef _Float16 half8 __attribute__((ext_vector_type(8)));
typedef _Float16 half4 __attribute__((ext_vector_type(4)));
typedef float floatx4 __attribute__((ext_vector_type(4)));

// Exact codebook norms (fp64 -> fp32); optional fp16 codebook copy (H);
// block 0 also zero-inits the accumulators.
template<bool CVT>
__global__ __launch_bounds__(64) void prep_kernel(const float* __restrict__ cb,
                                                  float* __restrict__ cn,
                                                  _Float16* __restrict__ cbh,
                                                  double* __restrict__ sumsq,
                                                  int* __restrict__ sumidx,
                                                  unsigned* __restrict__ done) {
  const int k = blockIdx.x, lane = threadIdx.x;
  if (k == 0 && lane == 0) { *sumsq = 0.0; *sumidx = 0; *done = 0u; }
  float4 v = *(const float4*)(cb + (size_t)k * DDIM + lane * 4);
  if constexpr (CVT) {
    half4 h;
    h[0] = (_Float16)v.x; h[1] = (_Float16)v.y;
    h[2] = (_Float16)v.z; h[3] = (_Float16)v.w;
    *(half4*)&cbh[(size_t)k * DDIM + lane * 4] = h;
  }
  double s = (double)v.x * v.x + (double)v.y * v.y
           + (double)v.z * v.z + (double)v.w * v.w;
  #pragma unroll
  for (int off = 32; off; off >>= 1) s += __shfl_down(s, off);
  if (lane == 0) cn[k] = (float)s;
}

// Block = 256 thr / 4 waves / 64 rows. Grid 512 = 2 blocks/CU (LDS ~42 KB).
// Stage = 32 codebook entries x 256 dims fp16-hi in 32xBSTR layout, dbuf.
template<bool H>
__global__ __launch_bounds__(256, 2) void fused_kernel(
    const float* __restrict__ x,
    const float* __restrict__ cb,
    const _Float16* __restrict__ cbh,
    const float* __restrict__ cn,
    float* __restrict__ zq_out,
    float* __restrict__ idx_out,
    float* __restrict__ out_loss,
    float* __restrict__ out_perp,
    double* __restrict__ sumsq,
    int* __restrict__ sumidx,
    unsigned* __restrict__ done) {
  __shared__ __align__(16) _Float16 bs[2][32 * BSTR];  // 2 x 16.9 KB tiles
  __shared__ float cn_lds[KCB];
  __shared__ int   bidx[64];     // best index (provisional -> final)
  __shared__ int   clist[64][8]; // candidate col indices per row
  __shared__ int   ccnt[64];     // candidate count (+64 if lane saturated)
  __shared__ __align__(16) float xrow[DDIM];
  __shared__ int   flist[64];    // full-rescan rows
  __shared__ int   nflag;
  __shared__ float wred[4];
  __shared__ double rv[4];
  __shared__ int    ri[4];

  const int tid = threadIdx.x;
  const int lane = tid & 63;
  const int w = tid >> 6;        // wave 0..3: rows w*16 .. +15
  const int q = lane >> 4;       // quad
  const int tx = lane & 15;
  const int row0 = blockIdx.x * 64;

  // ---- A fragments (-2x, hi+lo): lane holds rows row0+w*16+tx ----
  half8 a_hi[8], a_lo[8];
  {
    const float* xp = x + (size_t)(row0 + w * 16 + tx) * DDIM + q * 8;
    #pragma unroll
    for (int s = 0; s < 8; ++s) {
      float4 v0 = *(const float4*)(xp + s * 32);
      float4 v1 = *(const float4*)(xp + s * 32 + 4);
      half8 h, l;
      _Float16 t; float sx;
      sx = -2.f * v0.x; t = (_Float16)sx; h[0] = t; l[0] = (_Float16)(sx - (float)t);
      sx = -2.f * v0.y; t = (_Float16)sx; h[1] = t; l[1] = (_Float16)(sx - (float)t);
      sx = -2.f * v0.z; t = (_Float16)sx; h[2] = t; l[2] = (_Float16)(sx - (float)t);
      sx = -2.f * v0.w; t = (_Float16)sx; h[3] = t; l[3] = (_Float16)(sx - (float)t);
      sx = -2.f * v1.x; t = (_Float16)sx; h[4] = t; l[4] = (_Float16)(sx - (float)t);
      sx = -2.f * v1.y; t = (_Float16)sx; h[5] = t; l[5] = (_Float16)(sx - (float)t);
      sx = -2.f * v1.z; t = (_Float16)sx; h[6] = t; l[6] = (_Float16)(sx - (float)t);
      sx = -2.f * v1.w; t = (_Float16)sx; h[7] = t; l[7] = (_Float16)(sx - (float)t);
      a_hi[s] = h; a_lo[s] = l;
    }
  }
  #pragma unroll
  for (int i = 0; i < 4; ++i) cn_lds[tid + 256 * i] = cn[tid + 256 * i];
  if (tid == 0) nflag = 0;
  if (tid < 64) ccnt[tid] = 0;

  // stage ct covers entries ct*32..+31 (8192 halves). 16B unit u = tid+256*i
  half8 vld[4];
  float4 vldf[8];
  auto load_stage = [&](int ct) {
    #pragma unroll
    for (int i = 0; i < 4; ++i) {
      int u = tid + 256 * i;
      if constexpr (H) {
        vld[i] = *(const half8*)&cbh[(size_t)ct * 8192 + (size_t)u * 8];
      } else {
        const float* src = cb + (size_t)ct * 8192 + (size_t)u * 8;
        vldf[2 * i]     = *(const float4*)src;
        vldf[2 * i + 1] = *(const float4*)(src + 4);
      }
    }
  };
  auto write_stage = [&](int buf) {
    #pragma unroll
    for (int i = 0; i < 4; ++i) {
      int u = tid + 256 * i;
      int e = u >> 5, c = u & 31;
      if constexpr (H) {
        *(half8*)&bs[buf][e * BSTR + c * 8] = vld[i];
      } else {
        float4 v0 = vldf[2 * i], v1 = vldf[2 * i + 1];
        half8 h;
        h[0] = (_Float16)v0.x; h[1] = (_Float16)v0.y;
        h[2] = (_Float16)v0.z; h[3] = (_Float16)v0.w;
        h[4] = (_Float16)v1.x; h[5] = (_Float16)v1.y;
        h[6] = (_Float16)v1.z; h[7] = (_Float16)v1.w;
        *(half8*)&bs[buf][e * BSTR + c * 8] = h;
      }
    }
  };

  // per-lane sorted top-4 (value, col) per owned row r
  float tv[4][4];
  int   ti[4][4];
  #pragma unroll
  for (int r = 0; r < 4; ++r)
    #pragma unroll
    for (int j = 0; j < 4; ++j) { tv[r][j] = INFINITY; ti[r][j] = 0; }

  load_stage(0);
  for (int st = 0; st < 32; ++st) {
    const int buf = st & 1;
    write_stage(buf);            // consumes loads issued last iter (vmcnt wait)
    __syncthreads();             // tile visible; prev tile's readers done
    if (st + 1 < 32) load_stage(st + 1);   // in flight across compute(st)

    floatx4 ahh[2], alh[2];
    #pragma unroll
    for (int ci = 0; ci < 2; ++ci) {
      ahh[ci] = (floatx4){0.f, 0.f, 0.f, 0.f};
      alh[ci] = (floatx4){0.f, 0.f, 0.f, 0.f};
    }

    #pragma unroll
    for (int s = 0; s < 8; ++s) {
      #pragma unroll
      for (int ci = 0; ci < 2; ++ci) {
        half8 bh = *(const half8*)&bs[buf][(ci * 16 + tx) * BSTR + (s * 4 + q) * 8];
        ahh[ci] = __builtin_amdgcn_mfma_f32_16x16x32_f16(a_hi[s], bh, ahh[ci], 0, 0, 0);
        alh[ci] = __builtin_amdgcn_mfma_f32_16x16x32_f16(a_lo[s], bh, alh[ci], 0, 0, 0);
      }
    }

    // epilogue: C/D layout col=lane&15, row=q*4+reg; dist = cn + (-2x . b)
    // sorted top-4 insert (ties keep earlier/lower col -> np first-min)
    #pragma unroll
    for (int ci = 0; ci < 2; ++ci) {
      int col = st * 32 + ci * 16 + tx;
      float cnv = cn_lds[col];
      #pragma unroll
      for (int r = 0; r < 4; ++r) {
        float dist = cnv + (ahh[ci][r] + alh[ci][r]);
        if (dist < tv[r][3]) {
          if (dist < tv[r][0]) {
            tv[r][3] = tv[r][2]; ti[r][3] = ti[r][2];
            tv[r][2] = tv[r][1]; ti[r][2] = ti[r][1];
            tv[r][1] = tv[r][0]; ti[r][1] = ti[r][0];
            tv[r][0] = dist; ti[r][0] = col;
          } else if (dist < tv[r][1]) {
            tv[r][3] = tv[r][2]; ti[r][3] = ti[r][2];
            tv[r][2] = tv[r][1]; ti[r][2] = ti[r][1];
            tv[r][1] = dist; ti[r][1] = col;
          } else if (dist < tv[r][2]) {
            tv[r][3] = tv[r][2]; ti[r][3] = ti[r][2];
            tv[r][2] = dist; ti[r][2] = col;
          } else {
            tv[r][3] = dist; ti[r][3] = col;
          }
        }
      }
    }
  }

  // ---- (v1,i1) reduce across the 16 tx-lanes of each quad + broadcast ----
  #pragma unroll
  for (int r = 0; r < 4; ++r) {
    float bv = tv[r][0]; int bi = ti[r][0];
    #pragma unroll
    for (int off = 8; off; off >>= 1) {
      float ov = __shfl_down(bv, off, 16);
      int   oi = __shfl_down(bi, off, 16);
      if (ov < bv || (ov == bv && oi < bi)) { bv = ov; bi = oi; }
    }
    bv = __shfl(bv, 0, 16);      // broadcast winner to all 16 lanes
    bi = __shfl(bi, 0, 16);
    int R = w * 16 + q * 4 + r;
    if (tx == 0) bidx[R] = bi;
    // push candidates: local entries within TAU of v1, excluding (v1,i1)
    float thresh = bv + TAU;
    #pragma unroll
    for (int j = 0; j < 4; ++j) {
      if (tv[r][j] < thresh && !(tv[r][j] == bv && ti[r][j] == bi)) {
        int p = atomicAdd(&ccnt[R], 1);
        if (p < 8) clist[R][p] = ti[r][j];
      }
    }
    if (tv[r][3] < thresh)       // lane saturated: eviction hazard -> full
      atomicAdd(&ccnt[R], 64);
  }
  __syncthreads();

  if (tid < 64 && ccnt[tid] > 7) {
    int p = atomicAdd(&nflag, 1);
    flist[p] = tid;
  }
  __syncthreads();

  // ---- full fp64 re-scan (P ~ 1e-5/block; correctness net only) ----
  for (int f = 0; f < nflag; ++f) {
    int r = flist[f];
    if (tid < 64) {
      float4 v = *(const float4*)(x + (size_t)(row0 + r) * DDIM + tid * 4);
      xrow[tid * 4 + 0] = v.x; xrow[tid * 4 + 1] = v.y;
      xrow[tid * 4 + 2] = v.z; xrow[tid * 4 + 3] = v.w;
    }
    __syncthreads();
    double bd = 1e300; int bi = 0;
    #pragma unroll
    for (int j = 0; j < 4; ++j) {
      int c = tid * 4 + j;                      // ascending: strict < keeps low
      const float* cp = cb + (size_t)c * DDIM;
      double s0 = 0.0, s1 = 0.0, s2 = 0.0, s3 = 0.0;
      for (int d = 0; d < DDIM; d += 4) {
        float4 cv = *(const float4*)(cp + d);
        float4 xv = *(const float4*)&xrow[d];   // LDS broadcast (same addr)
        double d0 = (double)xv.x - (double)cv.x; s0 = fma(d0, d0, s0);
        double d1 = (double)xv.y - (double)cv.y; s1 = fma(d1, d1, s1);
        double d2 = (double)xv.z - (double)cv.z; s2 = fma(d2, d2, s2);
        double d3 = (double)xv.w - (double)cv.w; s3 = fma(d3, d3, s3);
      }
      double s = (s0 + s1) + (s2 + s3);
      if (s < bd) { bd = s; bi = c; }
    }
    #pragma unroll
    for (int off = 32; off; off >>= 1) {
      double ov = __shfl_down(bd, off);
      int oi = __shfl_down(bi, off);
      if (ov < bd || (ov == bd && oi < bi)) { bd = ov; bi = oi; }
    }
    if (lane == 0) { rv[w] = bd; ri[w] = bi; }
    __syncthreads();
    if (tid == 0) {
      double bv = rv[0]; int bix = ri[0];
      #pragma unroll
      for (int ww = 1; ww < 4; ++ww)
        if (rv[ww] < bv || (rv[ww] == bv && ri[ww] < bix)) { bv = rv[ww]; bix = ri[ww]; }
      bidx[r] = bix;
    }
    __syncthreads();
  }

  // ---- fp64 tournament over candidate list; waves take rows in parallel ----
  for (int r = w; r < 64; r += 4) {
    int c = ccnt[r];
    if (c == 0 || c > 7) continue;              // 0: done; >7: full handled
    int winner = bidx[r];
    for (int t = 0; t < c; ++t) {
      int cB = clist[r][t];
      int ccol = (lane >= 32) ? cB : winner;
      int ld = lane & 31;                       // 32 lanes x 8 dims each
      const float* xp = x  + (size_t)(row0 + r) * DDIM + ld * 8;
      const float* cp = cb + (size_t)ccol * DDIM + ld * 8;
      double s = 0.0;
      #pragma unroll
      for (int j = 0; j < 8; j += 4) {
        float4 xv = *(const float4*)(xp + j);
        float4 cv = *(const float4*)(cp + j);
        double d0 = (double)xv.x - (double)cv.x; s = fma(d0, d0, s);
        double d1 = (double)xv.y - (double)cv.y; s = fma(d1, d1, s);
        double d2 = (double)xv.z - (double)cv.z; s = fma(d2, d2, s);
        double d3 = (double)xv.w - (double)cv.w; s = fma(d3, d3, s);
      }
      #pragma unroll
      for (int off = 16; off; off >>= 1) s += __shfl_xor(s, off);  // 32-lane halves
      double dA = __shfl(s, 0), dB = __shfl(s, 32);
      if (dB < dA || (dB == dA && cB < winner)) winner = cB;  // uniform
    }
    if (lane == 0) bidx[r] = winner;
  }
  __syncthreads();

  if (tid < 64) idx_out[row0 + tid] = (float)bidx[tid];

  // ---- gather: z_q rows (exact fp32 copies) + loss partial ----
  float lsum = 0.f;
  #pragma unroll 4
  for (int it = 0; it < 16; ++it) {
    int g = tid + 256 * it;        // 4096 float4 groups = 64 rows x 64 groups
    int r = g >> 6;
    int c4 = (g & 63) << 2;
    int k = bidx[r] & (KCB - 1);
    float4 cv = *(const float4*)(cb + (size_t)k * DDIM + c4);
    float4 xv = *(const float4*)(x + (size_t)(row0 + r) * DDIM + c4);
    float d0 = cv.x - xv.x, d1 = cv.y - xv.y, d2 = cv.z - xv.z, d3 = cv.w - xv.w;
    lsum = fmaf(d0, d0, lsum); lsum = fmaf(d1, d1, lsum);
    lsum = fmaf(d2, d2, lsum); lsum = fmaf(d3, d3, lsum);
    *(float4*)(zq_out + (size_t)(row0 + r) * DDIM + c4) = cv;
  }
  #pragma unroll
  for (int off = 32; off; off >>= 1) lsum += __shfl_down(lsum, off);
  if (lane == 0) wred[w] = lsum;
  __syncthreads();
  if (tid == 0) {
    double ls = (double)wred[0] + (double)wred[1]
              + (double)wred[2] + (double)wred[3];
    atomicAdd(sumsq, ls);
    int si = 0;
    #pragma unroll 8
    for (int r = 0; r < 64; ++r) si += bidx[r] & (KCB - 1);
    atomicAdd(sumidx, si);

    // ---- last block finalizes loss/perplexity (r5/r9-validated pattern) ----
    __threadfence();                            // order our adds before 'done'
    unsigned prev = atomicAdd(done, 1u);
    if (prev == gridDim.x - 1) {
      __threadfence();
      double ss = atomicAdd(sumsq, 0.0);        // device-scope atomic read
      int    sidx = atomicAdd(sumidx, 0);
      // loss = mean(sg(zq)-x)^2 + 0.25*mean(zq-sg(x))^2 = 1.25 * MSE
      double loss = 1.25 * ss / 8388608.0;
      double e_min = (double)sidx / 32768.0;    // scalar mean of indices
      double perp = exp(-e_min * log(e_min + 1e-10));
      *out_loss = (float)loss;
      *out_perp = (float)perp;
    }
  }
}

extern "C" void kernel_launch(void* const* d_in, const int* in_sizes, int n_in,
                              void* d_out, int out_size, void* d_ws, size_t ws_size,
                              hipStream_t stream) {
  const float* x  = (const float*)d_in[0];   // [32768, 256] fp32
  const float* cb = (const float*)d_in[1];   // [1024, 256] fp32
  float* out = (float*)d_out;
  float* out_loss = out;                  // [0]
  float* out_zq   = out + 1;              // [1 .. 8388608]
  float* out_perp = out + 1 + 8388608;    // [8388609]
  float* out_idx  = out + 2 + 8388608;    // [8388610 ..]

  double*   sumsq  = (double*)d_ws;
  int*      sumidx = (int*)((char*)d_ws + 8);
  unsigned* done   = (unsigned*)((char*)d_ws + 12);
  float*    cn     = (float*)((char*)d_ws + 64);        // 4 KB
  _Float16* cbh    = (_Float16*)((char*)d_ws + 8192);   // 512 KB

  // ws_size is launch-invariant => deterministic branch (r7/r9 ran H=true).
  const bool useH = ws_size >= (size_t)(8192 + 524288);

  if (useH) {
    hipLaunchKernelGGL(prep_kernel<true>, dim3(KCB), dim3(64), 0, stream,
                       cb, cn, cbh, sumsq, sumidx, done);
    hipLaunchKernelGGL(fused_kernel<true>, dim3(NROWS / 64), dim3(256), 0, stream,
                       x, cb, cbh, cn, out_zq, out_idx, out_loss, out_perp,
                       sumsq, sumidx, done);
  } else {
    hipLaunchKernelGGL(prep_kernel<false>, dim3(KCB), dim3(64), 0, stream,
                       cb, cn, cbh, sumsq, sumidx, done);
    hipLaunchKernelGGL(fused_kernel<false>, dim3(NROWS / 64), dim3(256), 0, stream,
                       x, cb, cbh, cn, out_zq, out_idx, out_loss, out_perp,
                       sumsq, sumidx, done);
  }
}